// Round 1
// baseline (769.530 us; speedup 1.0000x reference)
//
#include <hip/hip_runtime.h>
#include <stdint.h>

// GalerkinBlock: x -> LN1 -> qkv -> LN(k),LN(v) -> ctx=K^T V -> attn=Q ctx*scale
//              -> proj(+x) = x1 -> LN2 -> mlp(gelu) -> x1 + mlp
// B=4 N=8192 C=512 H=4 D=128 HID=2048. All GEMMs bf16 MFMA (16x16x32), fp32 accum.

#define B_    4
#define N_    8192
#define C_    512
#define H_    4
#define D_    128
#define HID_  2048
#define M_    (B_*N_)          // 32768 rows
#define EPS_  1e-5f
#define SCALE_ 0.08838834764831845f   // D^-0.5

typedef unsigned short u16;
typedef __attribute__((ext_vector_type(8))) __bf16 bfrag_t;  // MFMA A/B frag (4 VGPRs)
typedef __attribute__((ext_vector_type(4))) float  f4_t;     // MFMA C/D frag

__device__ __forceinline__ float bf2f(u16 a) {
    unsigned int u = ((unsigned int)a) << 16; float f;
    __builtin_memcpy(&f, &u, 4); return f;
}
__device__ __forceinline__ u16 f2bf(float f) {
    unsigned int u; __builtin_memcpy(&u, &f, 4);
    u += 0x7FFFu + ((u >> 16) & 1u);             // round-nearest-even
    return (u16)(u >> 16);
}

// async 16B global->LDS (lands at ldsbase + lane*16)
__device__ __forceinline__ void gld16(u16* lds, const u16* g) {
    void* gp = const_cast<u16*>(g);
    __builtin_amdgcn_global_load_lds((__attribute__((address_space(1))) void*)gp,
                                     (__attribute__((address_space(3))) void*)lds,
                                     16, 0, 0);
}

// ---------------- weight transpose+convert: fp32 [K,Ncols] -> bf16 [Ncols,K] ----
__global__ void wtrans(const float* __restrict__ in, u16* __restrict__ out,
                       int K, int Ncols) {
    long idx = (long)blockIdx.x * 256 + threadIdx.x;
    long total = (long)K * Ncols;
    if (idx >= total) return;
    int k = (int)(idx % K), n = (int)(idx / K);
    out[idx] = f2bf(in[(long)k * Ncols + n]);    // out[n*K+k] coalesced write
}

// ---------------- row LayerNorm over 512 fp32 -> bf16 --------------------------
__global__ __launch_bounds__(256)
void ln_rows(const float* __restrict__ in, const float* __restrict__ w,
             const float* __restrict__ b, u16* __restrict__ out) {
    long row = blockIdx.x;
    int t = threadIdx.x;
    const float* p = in + row * 512;
    float v0 = p[t], v1 = p[t + 256];
    float s = v0 + v1, q = v0 * v0 + v1 * v1;
    #pragma unroll
    for (int o = 32; o >= 1; o >>= 1) { s += __shfl_xor(s, o, 64); q += __shfl_xor(q, o, 64); }
    __shared__ float sh[8];
    int wv = t >> 6, l = t & 63;
    if (l == 0) { sh[wv] = s; sh[4 + wv] = q; }
    __syncthreads();
    s = sh[0] + sh[1] + sh[2] + sh[3];
    q = sh[4] + sh[5] + sh[6] + sh[7];
    float mu = s * (1.f / 512.f);
    float var = q * (1.f / 512.f) - mu * mu;
    float rs = rsqrtf(var + EPS_);
    out[row * 512 + t]       = f2bf((v0 - mu) * rs * w[t] + b[t]);
    out[row * 512 + t + 256] = f2bf((v1 - mu) * rs * w[t + 256] + b[t + 256]);
}

// ---------------- LN over D=128 for k,v + transpose to [b,h][D][N] -------------
__global__ __launch_bounds__(256)
void lnkv(const u16* __restrict__ qkv,
          const float* __restrict__ kw, const float* __restrict__ kb,
          const float* __restrict__ vw, const float* __restrict__ vb,
          u16* __restrict__ kT, u16* __restrict__ vT) {
    int bh = blockIdx.x;                 // b*H+h
    int b = bh >> 2, h = bh & 3;
    int n0 = blockIdx.y * 64;
    int wv = threadIdx.x >> 6, l = threadIdx.x & 63;
    __shared__ u16 lk[128 * 68], lv[128 * 68];   // stride 68: 2-way bank alias (free)

    for (int r = wv; r < 64; r += 4) {
        long base = ((long)b * N_ + n0 + r) * 1536 + h * 128;
        {   // k at column block 512
            float x0 = bf2f(qkv[base + 512 + l]), x1 = bf2f(qkv[base + 512 + 64 + l]);
            float s = x0 + x1, q = x0 * x0 + x1 * x1;
            #pragma unroll
            for (int o = 32; o >= 1; o >>= 1) { s += __shfl_xor(s, o, 64); q += __shfl_xor(q, o, 64); }
            float mu = s * (1.f / 128.f), var = q * (1.f / 128.f) - mu * mu;
            float rs = rsqrtf(var + EPS_);
            lk[l * 68 + r]        = f2bf((x0 - mu) * rs * kw[l] + kb[l]);
            lk[(l + 64) * 68 + r] = f2bf((x1 - mu) * rs * kw[l + 64] + kb[l + 64]);
        }
        {   // v at column block 1024
            float x0 = bf2f(qkv[base + 1024 + l]), x1 = bf2f(qkv[base + 1024 + 64 + l]);
            float s = x0 + x1, q = x0 * x0 + x1 * x1;
            #pragma unroll
            for (int o = 32; o >= 1; o >>= 1) { s += __shfl_xor(s, o, 64); q += __shfl_xor(q, o, 64); }
            float mu = s * (1.f / 128.f), var = q * (1.f / 128.f) - mu * mu;
            float rs = rsqrtf(var + EPS_);
            lv[l * 68 + r]        = f2bf((x0 - mu) * rs * vw[l] + vb[l]);
            lv[(l + 64) * 68 + r] = f2bf((x1 - mu) * rs * vw[l + 64] + vb[l + 64]);
        }
    }
    __syncthreads();
    long obase = (long)bh * D_ * N_;
    #pragma unroll 4
    for (int i = 0; i < 32; i++) {
        int idx = i * 256 + threadIdx.x;
        int d = idx >> 6, nn = idx & 63;
        kT[obase + (long)d * N_ + n0 + nn] = lk[d * 68 + nn];
        vT[obase + (long)d * N_ + n0 + nn] = lv[d * 68 + nn];
    }
}

// ---------------- ctx finalize: ctxT[bh][e][d] = ctx[bh][d][e]*SCALE -> bf16 ----
__global__ void ctxfin(const float* __restrict__ ctx, u16* __restrict__ ctxT) {
    int idx = blockIdx.x * 256 + threadIdx.x;
    if (idx >= 16 * 16384) return;
    int z = idx >> 14, r = idx & 16383;
    int e = r >> 7, d = r & 127;
    ctxT[idx] = f2bf(ctx[(z << 14) + (d << 7) + e] * SCALE_);
}

// ---------------- core bf16 GEMM: C[m,n] = sum_k A[m,k]*Bt[n,k] (+epilogue) -----
// MODE 0: bf16 store          (attn)
// MODE 1: bf16 store + bias   (qkv)
// MODE 2: bf16 + bias + gelu  (mlp1)
// MODE 3: f32 + bias + resid  (proj, mlp2)
// MODE 4: f32 atomicAdd       (ctx split-K)
template<int MODE>
__global__ __launch_bounds__(256)
void gemm_bt(const u16* __restrict__ A, int lda, int64_t aZ1, int64_t aZ2, int zdiv,
             const u16* __restrict__ Bt, int ldb, int64_t bZ1, int64_t bZ2,
             void* __restrict__ outv, int ldo, int64_t oZ1, int64_t oZ2,
             const float* __restrict__ bias, const float* __restrict__ resid, int ldr,
             int K) {
    __shared__ __align__(16) u16 sA[128 * 32];
    __shared__ __align__(16) u16 sB[128 * 32];
    const int z = blockIdx.z;
    const int z1 = z / zdiv, z2 = z % zdiv;
    A  += z1 * aZ1 + z2 * aZ2;
    Bt += z1 * bZ1 + z2 * bZ2;
    const int64_t ooff = z1 * oZ1 + z2 * oZ2;
    const int m0 = blockIdx.x * 128, n0 = blockIdx.y * 128;
    const int tid = threadIdx.x, wave = tid >> 6, lane = tid & 63;
    const int wr = wave >> 1, wc = wave & 1;

    f4_t acc[4][4];
    #pragma unroll
    for (int i = 0; i < 4; i++)
        #pragma unroll
        for (int j = 0; j < 4; j++) acc[i][j] = (f4_t){0.f, 0.f, 0.f, 0.f};

    // staging: 512 16B-chunks per tile; chunk c -> row c>>2, col (c&3)*8
    const int c0 = wave * 64 + lane, c1 = 256 + wave * 64 + lane;
    const int r0 = c0 >> 2, e0 = (c0 & 3) * 8;
    const int r1 = c1 >> 2, e1 = (c1 & 3) * 8;
    const u16* a0 = A + (int64_t)(m0 + r0) * lda + e0;
    const u16* a1 = A + (int64_t)(m0 + r1) * lda + e1;
    const u16* b0 = Bt + (int64_t)(n0 + r0) * ldb + e0;
    const u16* b1 = Bt + (int64_t)(n0 + r1) * ldb + e1;
    u16* lA0 = &sA[wave * 512];        u16* lA1 = &sA[2048 + wave * 512];
    u16* lB0 = &sB[wave * 512];        u16* lB1 = &sB[2048 + wave * 512];

    const int qd = lane >> 4, md = lane & 15;
    int aoff[4], boff[4];
    #pragma unroll
    for (int i = 0; i < 4; i++) {
        aoff[i] = (wr * 64 + i * 16 + md) * 32 + qd * 8;
        boff[i] = (wc * 64 + i * 16 + md) * 32 + qd * 8;
    }

    for (int kt = 0; kt < K; kt += 32) {
        __syncthreads();                       // LDS free (prev reads drained)
        gld16(lA0, a0 + kt);  gld16(lA1, a1 + kt);
        gld16(lB0, b0 + kt);  gld16(lB1, b1 + kt);
        __syncthreads();                       // vmcnt(0) drain: tiles visible
        bfrag_t af[4], bf[4];
        #pragma unroll
        for (int i = 0; i < 4; i++) af[i] = *(const bfrag_t*)&sA[aoff[i]];
        #pragma unroll
        for (int i = 0; i < 4; i++) bf[i] = *(const bfrag_t*)&sB[boff[i]];
        #pragma unroll
        for (int mi = 0; mi < 4; mi++)
            #pragma unroll
            for (int ni = 0; ni < 4; ni++)
                acc[mi][ni] = __builtin_amdgcn_mfma_f32_16x16x32_bf16(
                    af[mi], bf[ni], acc[mi][ni], 0, 0, 0);
    }

    // epilogue: C/D layout col = lane&15, row = (lane>>4)*4 + reg  [m89/m91]
    #pragma unroll
    for (int mi = 0; mi < 4; mi++) {
        #pragma unroll
        for (int r = 0; r < 4; r++) {
            int m = m0 + wr * 64 + mi * 16 + qd * 4 + r;
            int64_t rowo = ooff + (int64_t)m * ldo;
            #pragma unroll
            for (int ni = 0; ni < 4; ni++) {
                int n = n0 + wc * 64 + ni * 16 + md;
                float v = acc[mi][ni][r];
                if (MODE == 1 || MODE == 2 || MODE == 3) v += bias[n];
                if (MODE == 2) v = 0.5f * v * (1.f + erff(v * 0.70710678118654752f));
                if (MODE == 3) v += resid[(int64_t)m * ldr + n];
                if (MODE == 0 || MODE == 1 || MODE == 2)
                    ((u16*)outv)[rowo + n] = f2bf(v);
                else if (MODE == 3)
                    ((float*)outv)[rowo + n] = v;
                else
                    atomicAdd(&((float*)outv)[rowo + n], v);
            }
        }
    }
}

// ------------------------------- launcher --------------------------------------
extern "C" void kernel_launch(void* const* d_in, const int* in_sizes, int n_in,
                              void* d_out, int out_size, void* d_ws, size_t ws_size,
                              hipStream_t stream) {
    const float* x      = (const float*)d_in[0];
    const float* n1w    = (const float*)d_in[1];
    const float* n1b    = (const float*)d_in[2];
    const float* qkv_w  = (const float*)d_in[3];
    const float* qkv_b  = (const float*)d_in[4];
    const float* lnk_w  = (const float*)d_in[5];
    const float* lnk_b  = (const float*)d_in[6];
    const float* lnv_w  = (const float*)d_in[7];
    const float* lnv_b  = (const float*)d_in[8];
    const float* proj_w = (const float*)d_in[9];
    const float* proj_b = (const float*)d_in[10];
    const float* n2w    = (const float*)d_in[11];
    const float* n2b    = (const float*)d_in[12];
    const float* w1     = (const float*)d_in[13];
    const float* b1     = (const float*)d_in[14];
    const float* w2     = (const float*)d_in[15];
    const float* b2     = (const float*)d_in[16];
    float* out = (float*)d_out;                 // x1 lives here, then final

    // workspace layout (needs ~209.2 MB)
    char* ws = (char*)d_ws;
    u16*  qkvWT = (u16*)(ws + 0);               // [1536,512] bf16   1.5 MB
    u16*  projT = (u16*)(ws + 1572864);         // [512,512]         0.5 MB
    u16*  w1T   = (u16*)(ws + 2097152);         // [2048,512]        2 MB
    u16*  w2T   = (u16*)(ws + 4194304);         // [512,2048]        2 MB
    float* ctx  = (float*)(ws + 6291456);       // [16,128,128] f32  1 MB
    u16*  ctxT  = (u16*)(ws + 7340032);         // [16,128,128] bf16 0.5 MB
    u16*  bufA  = (u16*)(ws + 7864320);         // xn -> attnC -> h  32 MB
    u16*  qkv   = (u16*)(ws + 41418752);        // [32768,1536] bf16 96 MB
    u16*  hid   = (u16*)(ws + 41418752);        // overlays qkv+kT (dead by then)
    u16*  kT    = (u16*)(ws + 142082048);       // [16,128,8192] bf16 32 MB
    u16*  vT    = (u16*)(ws + 175636480);       // [16,128,8192] bf16 32 MB

    dim3 blk(256);

    // weights -> bf16 transposed [N,K]
    wtrans<<<dim3(512 * 1536 / 256), blk, 0, stream>>>(qkv_w, qkvWT, 512, 1536);
    wtrans<<<dim3(512 * 512 / 256),  blk, 0, stream>>>(proj_w, projT, 512, 512);
    wtrans<<<dim3(512 * 2048 / 256), blk, 0, stream>>>(w1, w1T, 512, 2048);
    wtrans<<<dim3(2048 * 512 / 256), blk, 0, stream>>>(w2, w2T, 2048, 512);

    // LN1: x -> xn (bufA)
    ln_rows<<<dim3(M_), blk, 0, stream>>>(x, n1w, n1b, bufA);

    // qkv = xn @ qkv_w + qkv_b   [32768,1536] bf16
    gemm_bt<1><<<dim3(M_ / 128, 1536 / 128, 1), blk, 0, stream>>>(
        bufA, 512, 0, 0, 1,  qkvWT, 512, 0, 0,
        (void*)qkv, 1536, 0, 0,  qkv_b, nullptr, 0, 512);

    // LN(k), LN(v) + transpose to [bh][D][N]
    lnkv<<<dim3(B_ * H_, N_ / 64), blk, 0, stream>>>(qkv, lnk_w, lnk_b, lnv_w, lnv_b, kT, vT);

    // ctx[bh] = K^T V  (split-K over 8 slices of 1024, fp32 atomic accumulate)
    hipMemsetAsync(ctx, 0, 16 * 128 * 128 * 4, stream);
    gemm_bt<4><<<dim3(1, 1, B_ * H_ * 8), blk, 0, stream>>>(
        kT, N_, (int64_t)D_ * N_, 1024, 8,  vT, N_, (int64_t)D_ * N_, 1024,
        (void*)ctx, 128, 16384, 0,  nullptr, nullptr, 0, 1024);
    ctxfin<<<dim3(16 * 16384 / 256), blk, 0, stream>>>(ctx, ctxT);

    // attn = q @ (ctx*SCALE)  -> attnC [b][n][h*D+e] (bufA)
    gemm_bt<0><<<dim3(N_ / 128, 1, B_ * H_), blk, 0, stream>>>(
        qkv, 1536, (int64_t)N_ * 1536, 128, 4,  ctxT, 128, 4 * 16384, 16384,
        (void*)bufA, 512, (int64_t)N_ * 512, 128,  nullptr, nullptr, 0, 128);

    // x1 = attnC @ proj_w + proj_b + x   -> d_out (fp32)
    gemm_bt<3><<<dim3(M_ / 128, 512 / 128, 1), blk, 0, stream>>>(
        bufA, 512, 0, 0, 1,  projT, 512, 0, 0,
        (void*)out, 512, 0, 0,  proj_b, x, 512, 512);

    // LN2: x1 -> h (bufA)
    ln_rows<<<dim3(M_), blk, 0, stream>>>(out, n2w, n2b, bufA);

    // hid = gelu(h @ w1 + b1)  [32768,2048] bf16
    gemm_bt<2><<<dim3(M_ / 128, HID_ / 128, 1), blk, 0, stream>>>(
        bufA, 512, 0, 0, 1,  w1T, 512, 0, 0,
        (void*)hid, HID_, 0, 0,  b1, nullptr, 0, 512);

    // out = x1 + hid @ w2 + b2   (resid = d_out read-before-write per thread)
    gemm_bt<3><<<dim3(M_ / 128, 512 / 128, 1), blk, 0, stream>>>(
        hid, HID_, 0, 0, 1,  w2T, HID_, 0, 0,
        (void*)out, 512, 0, 0,  b2, out, 512, HID_);
}

// Round 2
// 680.296 us; speedup vs baseline: 1.1312x; 1.1312x over previous
//
#include <hip/hip_runtime.h>
#include <stdint.h>

// GalerkinBlock: x -> LN1 -> qkv -> LN(k),LN(v) -> ctx=K^T V -> attn=Q ctx*scale
//              -> proj(+x) = x1 -> LN2 -> mlp(gelu) -> x1 + mlp
// B=4 N=8192 C=512 H=4 D=128 HID=2048. All GEMMs bf16 MFMA (16x16x32), fp32 accum.

#define B_    4
#define N_    8192
#define C_    512
#define H_    4
#define D_    128
#define HID_  2048
#define M_    (B_*N_)          // 32768 rows
#define EPS_  1e-5f
#define SCALE_ 0.08838834764831845f   // D^-0.5

typedef unsigned short u16;
typedef __attribute__((ext_vector_type(8))) __bf16 bfrag_t;  // MFMA A/B frag (4 VGPRs)
typedef __attribute__((ext_vector_type(4))) float  f4_t;     // MFMA C/D frag

__device__ __forceinline__ float bf2f(u16 a) {
    unsigned int u = ((unsigned int)a) << 16; float f;
    __builtin_memcpy(&f, &u, 4); return f;
}
__device__ __forceinline__ u16 f2bf(float f) {                // RNE (cold paths)
    unsigned int u; __builtin_memcpy(&u, &f, 4);
    u += 0x7FFFu + ((u >> 16) & 1u);
    return (u16)(u >> 16);
}
__device__ __forceinline__ u16 f2bf_fast(float f) {           // round-half-up (hot epilogue)
    unsigned int u; __builtin_memcpy(&u, &f, 4);
    return (u16)((u + 0x8000u) >> 16);
}

// branch-free tanh-approx GELU: x * sigmoid(2*0.79788456*(x + 0.044715 x^3))
// == x - x * rcp(exp2(x*(kB*x^2 + kA)) + 1); saturates correctly at +/-inf exp.
__device__ __forceinline__ float fast_gelu(float x) {
    const float kA = 2.3022084f;   // 2*0.7978845608*log2(e)
    const float kB = 0.1029435f;   // kA*0.044715
    float x2 = x * x;
    float e1 = __builtin_amdgcn_exp2f(x * (kB * x2 + kA));
    return x - x * __builtin_amdgcn_rcpf(e1 + 1.0f);
}

// async 16B global->LDS (lands at ldsbase + lane*16)
__device__ __forceinline__ void gld16(u16* lds, const u16* g) {
    void* gp = const_cast<u16*>(g);
    __builtin_amdgcn_global_load_lds((__attribute__((address_space(1))) void*)gp,
                                     (__attribute__((address_space(3))) void*)lds,
                                     16, 0, 0);
}

// ---------------- weight transpose+convert: fp32 [K,Ncols] -> bf16 [Ncols,K] ----
__global__ void wtrans(const float* __restrict__ in, u16* __restrict__ out,
                       int K, int Ncols) {
    long idx = (long)blockIdx.x * 256 + threadIdx.x;
    long total = (long)K * Ncols;
    if (idx >= total) return;
    int k = (int)(idx % K), n = (int)(idx / K);
    out[idx] = f2bf(in[(long)k * Ncols + n]);    // out[n*K+k] coalesced write
}

// ---------------- row LayerNorm over 512 fp32 -> bf16 --------------------------
__global__ __launch_bounds__(256)
void ln_rows(const float* __restrict__ in, const float* __restrict__ w,
             const float* __restrict__ b, u16* __restrict__ out) {
    long row = blockIdx.x;
    int t = threadIdx.x;
    const float* p = in + row * 512;
    float v0 = p[t], v1 = p[t + 256];
    float s = v0 + v1, q = v0 * v0 + v1 * v1;
    #pragma unroll
    for (int o = 32; o >= 1; o >>= 1) { s += __shfl_xor(s, o, 64); q += __shfl_xor(q, o, 64); }
    __shared__ float sh[8];
    int wv = t >> 6, l = t & 63;
    if (l == 0) { sh[wv] = s; sh[4 + wv] = q; }
    __syncthreads();
    s = sh[0] + sh[1] + sh[2] + sh[3];
    q = sh[4] + sh[5] + sh[6] + sh[7];
    float mu = s * (1.f / 512.f);
    float var = q * (1.f / 512.f) - mu * mu;
    float rs = rsqrtf(var + EPS_);
    out[row * 512 + t]       = f2bf((v0 - mu) * rs * w[t] + b[t]);
    out[row * 512 + t + 256] = f2bf((v1 - mu) * rs * w[t + 256] + b[t + 256]);
}

// ---------------- LN over D=128 for k,v + transpose to [b,h][D][N] -------------
__global__ __launch_bounds__(256)
void lnkv(const u16* __restrict__ qkv,
          const float* __restrict__ kw, const float* __restrict__ kb,
          const float* __restrict__ vw, const float* __restrict__ vb,
          u16* __restrict__ kT, u16* __restrict__ vT) {
    int bh = blockIdx.x;                 // b*H+h
    int b = bh >> 2, h = bh & 3;
    int n0 = blockIdx.y * 64;
    int wv = threadIdx.x >> 6, l = threadIdx.x & 63;
    __shared__ u16 lk[128 * 68], lv[128 * 68];   // stride 68: 2-way bank alias (free)

    for (int r = wv; r < 64; r += 4) {
        long base = ((long)b * N_ + n0 + r) * 1536 + h * 128;
        {   // k at column block 512
            float x0 = bf2f(qkv[base + 512 + l]), x1 = bf2f(qkv[base + 512 + 64 + l]);
            float s = x0 + x1, q = x0 * x0 + x1 * x1;
            #pragma unroll
            for (int o = 32; o >= 1; o >>= 1) { s += __shfl_xor(s, o, 64); q += __shfl_xor(q, o, 64); }
            float mu = s * (1.f / 128.f), var = q * (1.f / 128.f) - mu * mu;
            float rs = rsqrtf(var + EPS_);
            lk[l * 68 + r]        = f2bf((x0 - mu) * rs * kw[l] + kb[l]);
            lk[(l + 64) * 68 + r] = f2bf((x1 - mu) * rs * kw[l + 64] + kb[l + 64]);
        }
        {   // v at column block 1024
            float x0 = bf2f(qkv[base + 1024 + l]), x1 = bf2f(qkv[base + 1024 + 64 + l]);
            float s = x0 + x1, q = x0 * x0 + x1 * x1;
            #pragma unroll
            for (int o = 32; o >= 1; o >>= 1) { s += __shfl_xor(s, o, 64); q += __shfl_xor(q, o, 64); }
            float mu = s * (1.f / 128.f), var = q * (1.f / 128.f) - mu * mu;
            float rs = rsqrtf(var + EPS_);
            lv[l * 68 + r]        = f2bf((x0 - mu) * rs * vw[l] + vb[l]);
            lv[(l + 64) * 68 + r] = f2bf((x1 - mu) * rs * vw[l + 64] + vb[l + 64]);
        }
    }
    __syncthreads();
    long obase = (long)bh * D_ * N_;
    #pragma unroll 4
    for (int i = 0; i < 32; i++) {
        int idx = i * 256 + threadIdx.x;
        int d = idx >> 6, nn = idx & 63;
        kT[obase + (long)d * N_ + n0 + nn] = lk[d * 68 + nn];
        vT[obase + (long)d * N_ + n0 + nn] = lv[d * 68 + nn];
    }
}

// ---------------- ctx finalize: ctxT[bh][e][d] = ctx[bh][d][e]*SCALE -> bf16 ----
__global__ void ctxfin(const float* __restrict__ ctx, u16* __restrict__ ctxT) {
    int idx = blockIdx.x * 256 + threadIdx.x;
    if (idx >= 16 * 16384) return;
    int z = idx >> 14, r = idx & 16383;
    int e = r >> 7, d = r & 127;
    ctxT[idx] = f2bf(ctx[(z << 14) + (d << 7) + e] * SCALE_);
}

// ---------------- core bf16 GEMM: C[m,n] = sum_k A[m,k]*Bt[n,k] (+epilogue) -----
// MODE 0: bf16 store          (attn)
// MODE 1: bf16 store + bias   (qkv)
// MODE 2: bf16 + bias + gelu  (mlp1)
// MODE 3: f32 + bias + resid  (proj, mlp2)
// MODE 4: f32 atomicAdd       (ctx split-K)
template<int MODE, int KTOT, int ZDIV>
__global__ __launch_bounds__(256)
void gemm_bt(const u16* __restrict__ A, int lda, int64_t aZ1, int64_t aZ2,
             const u16* __restrict__ Bt, int ldb, int64_t bZ1, int64_t bZ2,
             void* __restrict__ outv, int ldo, int64_t oZ1, int64_t oZ2,
             const float* __restrict__ bias, const float* __restrict__ resid, int ldr) {
    __shared__ __align__(16) u16 sA[128 * 32];
    __shared__ __align__(16) u16 sB[128 * 32];
    const int z = blockIdx.z;
    const int z1 = z / ZDIV, z2 = z % ZDIV;
    A  += z1 * aZ1 + z2 * aZ2;
    Bt += z1 * bZ1 + z2 * bZ2;
    const int64_t ooff = z1 * oZ1 + z2 * oZ2;
    const int m0 = blockIdx.x * 128, n0 = blockIdx.y * 128;
    const int tid = threadIdx.x, wave = tid >> 6, lane = tid & 63;
    const int wr = wave >> 1, wc = wave & 1;

    f4_t acc[4][4];
    #pragma unroll
    for (int i = 0; i < 4; i++)
        #pragma unroll
        for (int j = 0; j < 4; j++) acc[i][j] = (f4_t){0.f, 0.f, 0.f, 0.f};

    // staging: 512 16B-chunks per tile; chunk c -> row c>>2, col (c&3)*8
    const int c0 = wave * 64 + lane, c1 = 256 + wave * 64 + lane;
    const int r0 = c0 >> 2, e0 = (c0 & 3) * 8;
    const int r1 = c1 >> 2, e1 = (c1 & 3) * 8;
    const u16* a0 = A + (int64_t)(m0 + r0) * lda + e0;
    const u16* a1 = A + (int64_t)(m0 + r1) * lda + e1;
    const u16* b0 = Bt + (int64_t)(n0 + r0) * ldb + e0;
    const u16* b1 = Bt + (int64_t)(n0 + r1) * ldb + e1;
    u16* lA0 = &sA[wave * 512];        u16* lA1 = &sA[2048 + wave * 512];
    u16* lB0 = &sB[wave * 512];        u16* lB1 = &sB[2048 + wave * 512];

    const int qd = lane >> 4, md = lane & 15;
    int aoff[4], boff[4];
    #pragma unroll
    for (int i = 0; i < 4; i++) {
        aoff[i] = (wr * 64 + i * 16 + md) * 32 + qd * 8;
        boff[i] = (wc * 64 + i * 16 + md) * 32 + qd * 8;
    }

    #pragma unroll 4
    for (int kt = 0; kt < KTOT; kt += 32) {
        __syncthreads();                       // LDS free (prev reads drained)
        gld16(lA0, a0 + kt);  gld16(lA1, a1 + kt);
        gld16(lB0, b0 + kt);  gld16(lB1, b1 + kt);
        __syncthreads();                       // vmcnt(0) drain: tiles visible
        bfrag_t af[4], bf[4];
        #pragma unroll
        for (int i = 0; i < 4; i++) af[i] = *(const bfrag_t*)&sA[aoff[i]];
        #pragma unroll
        for (int i = 0; i < 4; i++) bf[i] = *(const bfrag_t*)&sB[boff[i]];
        #pragma unroll
        for (int mi = 0; mi < 4; mi++)
            #pragma unroll
            for (int ni = 0; ni < 4; ni++)
                acc[mi][ni] = __builtin_amdgcn_mfma_f32_16x16x32_bf16(
                    af[mi], bf[ni], acc[mi][ni], 0, 0, 0);
    }

    // epilogue: C/D layout col = lane&15, row = (lane>>4)*4 + reg  [m89/m91]
    #pragma unroll
    for (int mi = 0; mi < 4; mi++) {
        #pragma unroll
        for (int r = 0; r < 4; r++) {
            int m = m0 + wr * 64 + mi * 16 + qd * 4 + r;
            int64_t rowo = ooff + (int64_t)m * ldo;
            #pragma unroll
            for (int ni = 0; ni < 4; ni++) {
                int n = n0 + wc * 64 + ni * 16 + md;
                float v = acc[mi][ni][r];
                if (MODE == 1 || MODE == 2 || MODE == 3) v += bias[n];
                if (MODE == 2) v = fast_gelu(v);
                if (MODE == 3) v += resid[(int64_t)m * ldr + n];
                if (MODE == 0 || MODE == 1 || MODE == 2)
                    ((u16*)outv)[rowo + n] = f2bf_fast(v);
                else if (MODE == 3)
                    ((float*)outv)[rowo + n] = v;
                else
                    atomicAdd(&((float*)outv)[rowo + n], v);
            }
        }
    }
}

// ------------------------------- launcher --------------------------------------
extern "C" void kernel_launch(void* const* d_in, const int* in_sizes, int n_in,
                              void* d_out, int out_size, void* d_ws, size_t ws_size,
                              hipStream_t stream) {
    const float* x      = (const float*)d_in[0];
    const float* n1w    = (const float*)d_in[1];
    const float* n1b    = (const float*)d_in[2];
    const float* qkv_w  = (const float*)d_in[3];
    const float* qkv_b  = (const float*)d_in[4];
    const float* lnk_w  = (const float*)d_in[5];
    const float* lnk_b  = (const float*)d_in[6];
    const float* lnv_w  = (const float*)d_in[7];
    const float* lnv_b  = (const float*)d_in[8];
    const float* proj_w = (const float*)d_in[9];
    const float* proj_b = (const float*)d_in[10];
    const float* n2w    = (const float*)d_in[11];
    const float* n2b    = (const float*)d_in[12];
    const float* w1     = (const float*)d_in[13];
    const float* b1     = (const float*)d_in[14];
    const float* w2     = (const float*)d_in[15];
    const float* b2     = (const float*)d_in[16];
    float* out = (float*)d_out;                 // x1 lives here, then final

    // workspace layout (needs ~209.2 MB)
    char* ws = (char*)d_ws;
    u16*  qkvWT = (u16*)(ws + 0);               // [1536,512] bf16   1.5 MB
    u16*  projT = (u16*)(ws + 1572864);         // [512,512]         0.5 MB
    u16*  w1T   = (u16*)(ws + 2097152);         // [2048,512]        2 MB
    u16*  w2T   = (u16*)(ws + 4194304);         // [512,2048]        2 MB
    float* ctx  = (float*)(ws + 6291456);       // [16,128,128] f32  1 MB
    u16*  ctxT  = (u16*)(ws + 7340032);         // [16,128,128] bf16 0.5 MB
    u16*  bufA  = (u16*)(ws + 7864320);         // xn -> attnC -> h  32 MB
    u16*  qkv   = (u16*)(ws + 41418752);        // [32768,1536] bf16 96 MB
    u16*  hid   = (u16*)(ws + 41418752);        // overlays qkv+kT (dead by then)
    u16*  kT    = (u16*)(ws + 142082048);       // [16,128,8192] bf16 32 MB
    u16*  vT    = (u16*)(ws + 175636480);       // [16,128,8192] bf16 32 MB

    dim3 blk(256);

    // weights -> bf16 transposed [N,K]
    wtrans<<<dim3(512 * 1536 / 256), blk, 0, stream>>>(qkv_w, qkvWT, 512, 1536);
    wtrans<<<dim3(512 * 512 / 256),  blk, 0, stream>>>(proj_w, projT, 512, 512);
    wtrans<<<dim3(512 * 2048 / 256), blk, 0, stream>>>(w1, w1T, 512, 2048);
    wtrans<<<dim3(2048 * 512 / 256), blk, 0, stream>>>(w2, w2T, 2048, 512);

    // LN1: x -> xn (bufA)
    ln_rows<<<dim3(M_), blk, 0, stream>>>(x, n1w, n1b, bufA);

    // qkv = xn @ qkv_w + qkv_b   [32768,1536] bf16
    gemm_bt<1, 512, 1><<<dim3(M_ / 128, 1536 / 128, 1), blk, 0, stream>>>(
        bufA, 512, 0, 0,  qkvWT, 512, 0, 0,
        (void*)qkv, 1536, 0, 0,  qkv_b, nullptr, 0);

    // LN(k), LN(v) + transpose to [bh][D][N]
    lnkv<<<dim3(B_ * H_, N_ / 64), blk, 0, stream>>>(qkv, lnk_w, lnk_b, lnv_w, lnv_b, kT, vT);

    // ctx[bh] = K^T V  (split-K over 16 slices of 512, fp32 atomic accumulate)
    hipMemsetAsync(ctx, 0, 16 * 128 * 128 * 4, stream);
    gemm_bt<4, 512, 16><<<dim3(1, 1, B_ * H_ * 16), blk, 0, stream>>>(
        kT, N_, (int64_t)D_ * N_, 512,  vT, N_, (int64_t)D_ * N_, 512,
        (void*)ctx, 128, 16384, 0,  nullptr, nullptr, 0);
    ctxfin<<<dim3(16 * 16384 / 256), blk, 0, stream>>>(ctx, ctxT);

    // attn = q @ (ctx*SCALE)  -> attnC [b][n][h*D+e] (bufA)
    gemm_bt<0, 128, 4><<<dim3(N_ / 128, 1, B_ * H_), blk, 0, stream>>>(
        qkv, 1536, (int64_t)N_ * 1536, 128,  ctxT, 128, 4 * 16384, 16384,
        (void*)bufA, 512, (int64_t)N_ * 512, 128,  nullptr, nullptr, 0);

    // x1 = attnC @ proj_w + proj_b + x   -> d_out (fp32)
    gemm_bt<3, 512, 1><<<dim3(M_ / 128, 512 / 128, 1), blk, 0, stream>>>(
        bufA, 512, 0, 0,  projT, 512, 0, 0,
        (void*)out, 512, 0, 0,  proj_b, x, 512);

    // LN2: x1 -> h (bufA)
    ln_rows<<<dim3(M_), blk, 0, stream>>>(out, n2w, n2b, bufA);

    // hid = gelu(h @ w1 + b1)  [32768,2048] bf16
    gemm_bt<2, 512, 1><<<dim3(M_ / 128, HID_ / 128, 1), blk, 0, stream>>>(
        bufA, 512, 0, 0,  w1T, 512, 0, 0,
        (void*)hid, HID_, 0, 0,  b1, nullptr, 0);

    // out = x1 + hid @ w2 + b2   (resid = d_out read-before-write per thread)
    gemm_bt<3, 2048, 1><<<dim3(M_ / 128, 512 / 128, 1), blk, 0, stream>>>(
        hid, HID_, 0, 0,  w2T, HID_, 0, 0,
        (void*)out, 512, 0, 0,  b2, out, 512);
}